// Round 2
// baseline (226.660 us; speedup 1.0000x reference)
//
#include <hip/hip_runtime.h>
#include <math.h>

// Problem constants
#define B_DIM 32
#define C_DIM 1024
#define HW 28
#define MAP (HW * HW)       // 784
#define NMASK 153           // 1 center + 19 radii * 4 quads * 2 (ring,circle)
#define NTERM 154           // + global max term
#define NRING 20            // ring index 0 (center) .. 19; r2>361 in NO mask

// ---------------- Stage 1: per-(b,c) binned maxima -> vt[b][m][c] ----------
// One wave (64 lanes) per (b,c) pair; 4 waves per block.
__global__ __launch_bounds__(256) void cac_stage1(const float* __restrict__ x,
                                                  float* __restrict__ vt) {
    __shared__ unsigned bins[4][4 * NRING];   // [wave][quad*20 + ring]
    __shared__ float    pref[4][4 * NRING];   // prefix max (circle masks)

    const int wave = threadIdx.x >> 6;
    const int lane = threadIdx.x & 63;
    const int pair = blockIdx.x * 4 + wave;   // 0 .. 32767 (grid exact)

    // zero-init bins (0u == 0.0f, which is also the mask-zero clamp)
    for (int i = threadIdx.x; i < 4 * 4 * NRING; i += 256)
        ((unsigned*)bins)[i] = 0u;
    __syncthreads();

    const float* xp = x + (size_t)pair * MAP;
    float gmax = -INFINITY;

    #pragma unroll
    for (int it = 0; it < 13; ++it) {
        int idx = it * 64 + lane;
        if (idx < MAP) {
            float v = xp[idx];
            gmax = fmaxf(gmax, v);
            if (v > 0.0f) {
                int i = idx / HW;          // row (height)
                int j = idx - i * HW;      // col (width)
                int dy = i - 14;           // y in reference
                int dx = j - 14;           // x in reference
                int r2 = dx * dx + dy * dy;
                unsigned bits = __float_as_uint(v);  // monotone for v>0
                if (r2 == 0) {
                    atomicMax(&bins[wave][0], bits);   // center bin (shared)
                } else if (r2 <= (NRING - 1) * (NRING - 1)) {  // r2>361: in NO mask
                    int ring = (int)ceilf(sqrtf((float)r2));  // 1..19
                    // quadrant order: (+,+), (-,+), (+,-), (-,-)  [sx*x>=0 & sy*y>=0]
                    if (dx >= 0 && dy >= 0) atomicMax(&bins[wave][0 * NRING + ring], bits);
                    if (dx <= 0 && dy >= 0) atomicMax(&bins[wave][1 * NRING + ring], bits);
                    if (dx >= 0 && dy <= 0) atomicMax(&bins[wave][2 * NRING + ring], bits);
                    if (dx <= 0 && dy <= 0) atomicMax(&bins[wave][3 * NRING + ring], bits);
                }
            }
        }
    }
    __syncthreads();

    // prefix max per quadrant (circle masks include the center for every quad)
    if (lane < 4) {
        float run = __uint_as_float(bins[wave][0]);   // center (>= 0)
        pref[wave][lane * NRING + 0] = run;
        for (int r = 1; r < NRING; ++r) {
            run = fmaxf(run, __uint_as_float(bins[wave][lane * NRING + r]));
            pref[wave][lane * NRING + r] = run;
        }
    }

    // wave-reduce the unclamped global max
    for (int off = 32; off; off >>= 1)
        gmax = fmaxf(gmax, __shfl_xor(gmax, off, 64));
    __syncthreads();

    // emit 154 terms: layout vt[b][m][c] (c contiguous)
    const int b = pair >> 10;
    const int c = pair & (C_DIM - 1);
    float* outp = vt + (size_t)b * NTERM * C_DIM + c;
    for (int k = lane; k < NTERM; k += 64) {
        float val;
        if (k == 0) {
            val = __uint_as_float(bins[wave][0]);          // center mask
        } else if (k == NMASK) {
            val = gmax;                                    // global (unclamped)
        } else {
            int t  = k - 1;
            int r  = (t >> 3) + 1;       // radius 1..19
            int q  = (t >> 1) & 3;       // quadrant
            val = (t & 1) ? pref[wave][q * NRING + r]                  // circle
                          : __uint_as_float(bins[wave][q * NRING + r]); // ring
        }
        outp[(size_t)k * C_DIM] = val;
    }
}

// ---------------- Stage 2: inverse norms per (b, m) ------------------------
__global__ __launch_bounds__(256) void cac_stage2(const float* __restrict__ vt,
                                                  float* __restrict__ invn) {
    const int bm = blockIdx.x;            // 0 .. 32*154-1
    const float* p = vt + (size_t)bm * C_DIM;
    float s = 0.0f;
    #pragma unroll
    for (int c = threadIdx.x; c < C_DIM; c += 256) {
        float v = p[c];
        s += v * v;
    }
    __shared__ float red[4];
    for (int off = 32; off; off >>= 1) s += __shfl_xor(s, off, 64);
    if ((threadIdx.x & 63) == 0) red[threadIdx.x >> 6] = s;
    __syncthreads();
    if (threadIdx.x == 0) {
        float t = red[0] + red[1] + red[2] + red[3];
        invn[bm] = 1.0f / (sqrtf(t) + 1e-6f);
    }
}

// ---------------- Stage 3: weighted accumulation over m --------------------
__global__ __launch_bounds__(256) void cac_stage3(const float* __restrict__ vt,
                                                  const float* __restrict__ invn,
                                                  float* __restrict__ out) {
    const int tid = blockIdx.x * 256 + threadIdx.x;   // 0..32767
    const int b = tid >> 10;
    const int c = tid & (C_DIM - 1);
    const float* p  = vt + (size_t)b * NTERM * C_DIM + c;
    const float* nv = invn + b * NTERM;
    float acc = 0.0f;
    #pragma unroll 4
    for (int m = 0; m < NTERM; ++m)
        acc += p[(size_t)m * C_DIM] * nv[m];   // nv wave-uniform -> scalar load
    out[tid] = acc;
}

extern "C" void kernel_launch(void* const* d_in, const int* in_sizes, int n_in,
                              void* d_out, int out_size, void* d_ws, size_t ws_size,
                              hipStream_t stream) {
    const float* x = (const float*)d_in[0];
    float* out = (float*)d_out;

    float* vt   = (float*)d_ws;                                   // 32*154*1024 fp32 = 20.2 MB
    float* invn = vt + (size_t)B_DIM * NTERM * C_DIM;             // 32*154 fp32

    cac_stage1<<<(B_DIM * C_DIM) / 4, 256, 0, stream>>>(x, vt);
    cac_stage2<<<B_DIM * NTERM, 256, 0, stream>>>(vt, invn);
    cac_stage3<<<(B_DIM * C_DIM) / 256, 256, 0, stream>>>(vt, invn, out);
}

// Round 3
// 177.027 us; speedup vs baseline: 1.2804x; 1.2804x over previous
//
#include <hip/hip_runtime.h>
#include <math.h>

// Problem constants
#define B_DIM 32
#define C_DIM 1024
#define HW 28
#define MAP (HW * HW)       // 784
#define NMASK 153
#define NTERM 154           // + global max term
#define NBIN 77             // 0=center, 1 + q*19 + (r-1), q in [0,4), r in [1,19]
#define DUMMY_BIN 77        // scratch slot for lanes with no second bin
#define MAXS 28             // max schedule slots per lane (static_assert-checked)

// ---------------------------------------------------------------------------
// Compile-time schedule: each lane of a wave owns 1-2 (quad,ring) bins and a
// padded pixel list. Pads duplicate a member pixel -> branch-free max.
// ---------------------------------------------------------------------------
struct Sched {
    unsigned short tab[MAXS][64];  // [slot][lane] -> pixel index (coalesced)
    unsigned char  split[64];      // slots < split feed binA, rest feed binB
    unsigned char  binA[64];
    unsigned char  binB[64];
    bool ok;
};

constexpr Sched build_sched() {
    Sched S{};
    short px[NBIN][40] = {};
    int   n[NBIN] = {};
    // enumerate bin membership (identical predicate to the verified kernel)
    for (int i = 0; i < 28; ++i)
        for (int j = 0; j < 28; ++j) {
            int dy = i - 14, dx = j - 14, r2 = dx * dx + dy * dy;
            int p = i * 28 + j;
            if (r2 == 0) { px[0][n[0]++] = (short)p; continue; }
            if (r2 > 361) continue;               // r2>361: in NO mask
            int r = 0; while (r * r < r2) ++r;    // ceil(sqrt), 1..19
            const int sx[4] = {1, -1, 1, -1}, sy[4] = {1, 1, -1, -1};
            for (int q = 0; q < 4; ++q)
                if (sx[q] * dx >= 0 && sy[q] * dy >= 0) {
                    int b = 1 + q * 19 + (r - 1);
                    px[b][n[b]++] = (short)p;
                }
        }
    // order bins by size descending
    int ord[NBIN] = {};
    for (int k = 0; k < NBIN; ++k) ord[k] = k;
    for (int a = 0; a < NBIN; ++a) {
        int best = a;
        for (int b2 = a + 1; b2 < NBIN; ++b2)
            if (n[ord[b2]] > n[ord[best]]) best = b2;
        int t = ord[a]; ord[a] = ord[best]; ord[best] = t;
    }
    S.ok = true;
    for (int k = 0; k < NBIN; ++k) if (n[k] < 1 || n[k] > 40) S.ok = false;
    // lane l gets bin ord[l]; lanes 51..63 get a second (small) bin ord[64+(63-l)]
    for (int l = 0; l < 64; ++l) {
        int bA = ord[l];
        int bB = (l >= 51) ? ord[64 + (63 - l)] : -1;
        int s = 0;
        for (int t = 0; t < n[bA] && s < MAXS; ++t) S.tab[s++][l] = (unsigned short)px[bA][t];
        S.split[l] = (unsigned char)s;
        S.binA[l]  = (unsigned char)bA;
        int fillpix;
        if (bB >= 0) {
            for (int t = 0; t < n[bB]; ++t) {
                if (s >= MAXS) { S.ok = false; break; }
                S.tab[s++][l] = (unsigned short)px[bB][t];
            }
            S.binB[l] = (unsigned char)bB;
            fillpix = px[bB][0];
        } else {
            S.binB[l] = DUMMY_BIN;
            fillpix = 406;  // center pixel: harmless pad
        }
        if (n[bA] > MAXS) S.ok = false;
        for (; s < MAXS; ++s) S.tab[s][l] = (unsigned short)fillpix;
    }
    return S;
}

static_assert(build_sched().ok, "schedule overflow / empty bin");
__constant__ Sched d_sched = build_sched();

// ---------------- Stage 1: per-(b,c) binned maxima -> vt[b][m][c] ----------
// One wave per (b,c); 4 waves per block. No atomics: constexpr CSR gather.
__global__ __launch_bounds__(256) void cac_stage1(const float* __restrict__ x,
                                                  float* __restrict__ vt) {
    __shared__ __align__(16) float smap[4][MAP];   // raw map per wave
    __shared__ float sbin[4][NBIN + 1];            // bin maxima (+dummy)
    __shared__ float spref[4][4][20];              // circle prefix per quad

    const int wave = threadIdx.x >> 6;
    const int lane = threadIdx.x & 63;
    const int pair = blockIdx.x * 4 + wave;        // (b,c), grid exact

    // ---- stage the map into LDS with float4 loads; fold global max ----
    const float4* xp4 = (const float4*)(x + (size_t)pair * MAP);  // 3136B-aligned
    float4* sm4 = (float4*)smap[wave];
    float gmax = -INFINITY;
    #pragma unroll
    for (int it = 0; it < 3; ++it) {               // 192 float4 = 768 floats
        float4 v = xp4[it * 64 + lane];
        sm4[it * 64 + lane] = v;
        gmax = fmaxf(fmaxf(gmax, fmaxf(v.x, v.y)), fmaxf(v.z, v.w));
    }
    if (lane < 4) {                                // tail: 16 floats
        float4 v = xp4[192 + lane];
        sm4[192 + lane] = v;
        gmax = fmaxf(fmaxf(gmax, fmaxf(v.x, v.y)), fmaxf(v.z, v.w));
    }
    __syncthreads();

    // ---- branch-free bin gather: lane owns 1-2 bins ----
    const int split = d_sched.split[lane];
    float m1 = 0.0f, m2 = 0.0f;   // init 0 == masked-max clamp (x*mask has zeros)
    #pragma unroll
    for (int s = 0; s < MAXS; ++s) {
        float v = smap[wave][d_sched.tab[s][lane]];
        if (s < split) m1 = fmaxf(m1, v);
        else           m2 = fmaxf(m2, v);
    }
    sbin[wave][d_sched.binA[lane]] = m1;
    sbin[wave][d_sched.binB[lane]] = m2;

    // wave-reduce the unclamped global max (covers all 784 incl. unbinned)
    #pragma unroll
    for (int off = 32; off; off >>= 1)
        gmax = fmaxf(gmax, __shfl_xor(gmax, off, 64));
    __syncthreads();

    // ---- circle prefix per quadrant (center included in every circle) ----
    if (lane < 4) {
        float run = sbin[wave][0];
        #pragma unroll
        for (int r = 1; r < 20; ++r) {
            run = fmaxf(run, sbin[wave][1 + lane * 19 + (r - 1)]);
            spref[wave][lane][r] = run;
        }
    }
    __syncthreads();

    // ---- emit 154 terms: layout vt[b][m][c] (c contiguous) ----
    const int b = pair >> 10;
    const int c = pair & (C_DIM - 1);
    float* outp = vt + (size_t)b * NTERM * C_DIM + c;
    for (int k = lane; k < NTERM; k += 64) {
        float val;
        if (k == 0) {
            val = sbin[wave][0];                       // center mask
        } else if (k == NMASK) {
            val = gmax;                                // global (unclamped)
        } else {
            int t = k - 1;
            int r = (t >> 3) + 1;                      // radius 1..19
            int q = (t >> 1) & 3;                      // quadrant
            val = (t & 1) ? spref[wave][q][r]          // circle
                          : sbin[wave][1 + q * 19 + (r - 1)];  // ring
        }
        outp[(size_t)k * C_DIM] = val;
    }
}

// ---------------- Stage 2: inverse norms per (b, m) ------------------------
__global__ __launch_bounds__(256) void cac_stage2(const float* __restrict__ vt,
                                                  float* __restrict__ invn) {
    const int bm = blockIdx.x;                 // 0 .. 32*154-1
    const float4* p = (const float4*)(vt + (size_t)bm * C_DIM);
    float4 v = p[threadIdx.x];                 // 256 threads x 4 = 1024
    float s = v.x * v.x + v.y * v.y + v.z * v.z + v.w * v.w;
    __shared__ float red[4];
    #pragma unroll
    for (int off = 32; off; off >>= 1) s += __shfl_xor(s, off, 64);
    if ((threadIdx.x & 63) == 0) red[threadIdx.x >> 6] = s;
    __syncthreads();
    if (threadIdx.x == 0) {
        float t = red[0] + red[1] + red[2] + red[3];
        invn[bm] = 1.0f / (sqrtf(t) + 1e-6f);
    }
}

// ---------------- Stage 3: weighted accumulation over m --------------------
__global__ __launch_bounds__(256) void cac_stage3(const float* __restrict__ vt,
                                                  const float* __restrict__ invn,
                                                  float* __restrict__ out) {
    const int tid = blockIdx.x * 256 + threadIdx.x;   // 0..32767
    const int b = tid >> 10;
    const int c = tid & (C_DIM - 1);
    const float* p  = vt + (size_t)b * NTERM * C_DIM + c;
    const float* nv = invn + b * NTERM;
    float acc0 = 0.0f, acc1 = 0.0f;
    #pragma unroll 7
    for (int m = 0; m < 154; m += 2) {                // 2 chains for ILP
        acc0 += p[(size_t)m * C_DIM] * nv[m];
        acc1 += p[(size_t)(m + 1) * C_DIM] * nv[m + 1];
    }
    out[tid] = acc0 + acc1;
}

extern "C" void kernel_launch(void* const* d_in, const int* in_sizes, int n_in,
                              void* d_out, int out_size, void* d_ws, size_t ws_size,
                              hipStream_t stream) {
    const float* x = (const float*)d_in[0];
    float* out = (float*)d_out;

    float* vt   = (float*)d_ws;                                   // 32*154*1024 fp32 = 20.2 MB
    float* invn = vt + (size_t)B_DIM * NTERM * C_DIM;             // 32*154 fp32

    cac_stage1<<<(B_DIM * C_DIM) / 4, 256, 0, stream>>>(x, vt);
    cac_stage2<<<B_DIM * NTERM, 256, 0, stream>>>(vt, invn);
    cac_stage3<<<(B_DIM * C_DIM) / 256, 256, 0, stream>>>(vt, invn, out);
}

// Round 4
// 167.715 us; speedup vs baseline: 1.3515x; 1.0555x over previous
//
#include <hip/hip_runtime.h>
#include <math.h>

// Problem constants
#define B_DIM 32
#define C_DIM 1024
#define HW 28
#define MAP 784
#define NMASK 153
#define NTERM 154          // 153 masks + global-max term
#define NROW 160           // padded row length (16B-aligned float4 rows; pads = 0)
#define NBIN 77            // 0=center, 1 + q*19 + (r-1)
#define DUMMY_BIN 77
#define MAX1 28            // slots for each lane's primary bin
#define MAX2 6             // slots for secondary (small) bins on lanes 51..63

// ---------------------------------------------------------------------------
// Compile-time gather schedule, bank-aware: per LDS-read slot, pixels are
// greedily assigned to minimize same-bank lanes (2-way aliasing is free on
// gfx950; >=4-way costs). Offsets are byte offsets into the wave's map.
// ---------------------------------------------------------------------------
struct Sched {
    unsigned short off1[MAX1][64];  // [slot][lane] byte offset, primary bin
    unsigned short off2[MAX2][64];  // [slot][lane] byte offset, secondary bin
    unsigned char  binA[64];
    unsigned char  binB[64];        // DUMMY_BIN for lanes without a 2nd bin
    bool ok;
};

constexpr Sched build_sched() {
    Sched S{};
    S.ok = true;
    short px[NBIN][40] = {};
    int   n[NBIN] = {};
    for (int i = 0; i < 28; ++i)
        for (int j = 0; j < 28; ++j) {
            int dy = i - 14, dx = j - 14, r2 = dx * dx + dy * dy;
            int p = i * 28 + j;
            if (r2 == 0) { px[0][n[0]++] = (short)p; continue; }
            if (r2 > 361) continue;            // r2>361: in NO mask
            int r = 0; while (r * r < r2) ++r; // ceil(sqrt), 1..19
            const int sx[4] = {1, -1, 1, -1}, sy[4] = {1, 1, -1, -1};
            for (int q = 0; q < 4; ++q)
                if (sx[q] * dx >= 0 && sy[q] * dy >= 0) {
                    int b = 1 + q * 19 + (r - 1);
                    if (n[b] >= 40) { S.ok = false; continue; }
                    px[b][n[b]++] = (short)p;
                }
        }
    // order bins by size descending
    int ord[NBIN] = {};
    for (int k = 0; k < NBIN; ++k) ord[k] = k;
    for (int a = 0; a < NBIN; ++a) {
        int best = a;
        for (int c = a + 1; c < NBIN; ++c)
            if (n[ord[c]] > n[ord[best]]) best = c;
        int t = ord[a]; ord[a] = ord[best]; ord[best] = t;
    }
    for (int l = 0; l < 64; ++l) {
        S.binA[l] = (unsigned char)ord[l];
        S.binB[l] = (l >= 51) ? (unsigned char)ord[64 + (l - 51)]
                              : (unsigned char)DUMMY_BIN;
        if (n[ord[l]] > MAX1) S.ok = false;
        if (l >= 51 && n[ord[64 + (l - 51)]] > MAX2) S.ok = false;
    }
    // greedy bank-aware placement, primary loop
    {
        bool used[64][40] = {};
        for (int s = 0; s < MAX1; ++s) {
            int bankcnt[32] = {};
            for (int l = 0; l < 64; ++l) {
                int bin = S.binA[l], cnt = n[bin];
                int bestp = 0, bestload = 1 << 30; bool haveUnused = false;
                for (int t = 0; t < cnt; ++t)
                    if (!used[l][t]) {
                        int load = bankcnt[px[bin][t] % 32];
                        if (!haveUnused || load < bestload) { haveUnused = true; bestload = load; bestp = t; }
                    }
                if (!haveUnused)
                    for (int t = 0; t < cnt; ++t) {
                        int load = bankcnt[px[bin][t] % 32];
                        if (load < bestload) { bestload = load; bestp = t; }
                    }
                int p = px[bin][bestp];
                if (haveUnused) used[l][bestp] = true;
                S.off1[s][l] = (unsigned short)(p * 4);
                bankcnt[p % 32]++;
            }
        }
        for (int l = 0; l < 64; ++l)
            for (int t = 0; t < n[S.binA[l]]; ++t)
                if (!used[l][t]) S.ok = false;       // every pixel placed
    }
    // secondary loop
    {
        bool used[64][40] = {};
        for (int s = 0; s < MAX2; ++s) {
            int bankcnt[32] = {};
            for (int l = 0; l < 64; ++l) {
                if (S.binB[l] == DUMMY_BIN) {        // pad read, result discarded
                    S.off2[s][l] = (unsigned short)((l % 32) * 4);
                    continue;
                }
                int bin = S.binB[l], cnt = n[bin];
                int bestp = 0, bestload = 1 << 30; bool haveUnused = false;
                for (int t = 0; t < cnt; ++t)
                    if (!used[l][t]) {
                        int load = bankcnt[px[bin][t] % 32];
                        if (!haveUnused || load < bestload) { haveUnused = true; bestload = load; bestp = t; }
                    }
                if (!haveUnused)
                    for (int t = 0; t < cnt; ++t) {
                        int load = bankcnt[px[bin][t] % 32];
                        if (load < bestload) { bestload = load; bestp = t; }
                    }
                int p = px[bin][bestp];
                if (haveUnused) used[l][bestp] = true;
                S.off2[s][l] = (unsigned short)(p * 4);
                bankcnt[p % 32]++;
            }
        }
        for (int l = 0; l < 64; ++l)
            if (S.binB[l] != DUMMY_BIN)
                for (int t = 0; t < n[S.binB[l]]; ++t)
                    if (!used[l][t]) S.ok = false;
    }
    return S;
}

static_assert(build_sched().ok, "schedule overflow / unplaced pixel");
__constant__ Sched d_sched = build_sched();

// ---------------- Stage A: terms + per-block squared partial sums ----------
// One wave per (b,c); 4 waves/block. vt row layout [pair][NROW] (coalesced).
__global__ __launch_bounds__(256) void cac_stageA(const float* __restrict__ x,
                                                  float* __restrict__ vt,
                                                  float* __restrict__ partial) {
    __shared__ __align__(16) float smap[4][MAP];
    __shared__ float sbin[4][NBIN + 1];
    __shared__ float spref[4][4][20];
    __shared__ float ssq[4][NROW];

    const int wave = threadIdx.x >> 6;
    const int lane = threadIdx.x & 63;
    const int pair = blockIdx.x * 4 + wave;         // grid exact: 32768 pairs

    // stage map via float4; fold unclamped global max (includes unbinned px)
    const float4* xp4 = (const float4*)(x + (size_t)pair * MAP);
    float4* sm4 = (float4*)smap[wave];
    float gmax = -INFINITY;
    #pragma unroll
    for (int it = 0; it < 3; ++it) {
        float4 v = xp4[it * 64 + lane];
        sm4[it * 64 + lane] = v;
        gmax = fmaxf(fmaxf(gmax, fmaxf(v.x, v.y)), fmaxf(v.z, v.w));
    }
    if (lane < 4) {
        float4 v = xp4[192 + lane];
        sm4[192 + lane] = v;
        gmax = fmaxf(fmaxf(gmax, fmaxf(v.x, v.y)), fmaxf(v.z, v.w));
    }
    __syncthreads();

    // single-accumulator gather loops (init 0 == masked-max clamp)
    const char* base = (const char*)smap[wave];
    float m1 = 0.0f, m2 = 0.0f;
    #pragma unroll
    for (int s = 0; s < MAX1; ++s)
        m1 = fmaxf(m1, *(const float*)(base + d_sched.off1[s][lane]));
    #pragma unroll
    for (int s = 0; s < MAX2; ++s)
        m2 = fmaxf(m2, *(const float*)(base + d_sched.off2[s][lane]));

    sbin[wave][d_sched.binA[lane]] = m1;
    sbin[wave][d_sched.binB[lane]] = m2;   // DUMMY_BIN slot absorbs pad lanes

    #pragma unroll
    for (int off = 32; off; off >>= 1)
        gmax = fmaxf(gmax, __shfl_xor(gmax, off, 64));
    __syncthreads();

    // circle prefix per quadrant (center included in every circle)
    if (lane < 4) {
        float run = sbin[wave][0];
        #pragma unroll
        for (int r = 1; r < 20; ++r) {
            run = fmaxf(run, sbin[wave][1 + lane * 19 + (r - 1)]);
            spref[wave][lane][r] = run;
        }
    }
    __syncthreads();

    // emit coalesced row vt[pair][0..159] + squares into LDS
    float* rowp = vt + (size_t)pair * NROW;
    #pragma unroll
    for (int i = 0; i < 3; ++i) {
        int k = lane + i * 64;
        if (k < NROW) {
            float val;
            if (k == 0) val = sbin[wave][0];                 // center mask
            else if (k == NMASK) val = gmax;                 // global (unclamped)
            else if (k < NMASK) {
                int t = k - 1, r = (t >> 3) + 1, q = (t >> 1) & 3;
                val = (t & 1) ? spref[wave][q][r]            // circle
                              : sbin[wave][1 + q * 19 + (r - 1)]; // ring
            } else val = 0.0f;                               // pad
            rowp[k] = val;
            ssq[wave][k] = val * val;
        }
    }
    __syncthreads();

    // per-block partial sum of squares (deterministic, no atomics)
    if (threadIdx.x < NROW) {
        int t = threadIdx.x;
        partial[(size_t)blockIdx.x * NROW + t] =
            ssq[0][t] + ssq[1][t] + ssq[2][t] + ssq[3][t];
    }
}

// ---------------- Stage B: reduce partials -> inverse norms ----------------
// One block per b; 256 blocks of A map to each b (pairs are sequential).
__global__ __launch_bounds__(192) void cac_stageB(const float* __restrict__ partial,
                                                  float* __restrict__ invn) {
    const int b = blockIdx.x, t = threadIdx.x;
    if (t >= NROW) return;
    const float* p = partial + (size_t)b * 256 * NROW + t;
    float s = 0.0f;
    #pragma unroll 8
    for (int r = 0; r < 256; ++r) s += p[(size_t)r * NROW];  // coalesced per r
    invn[b * NROW + t] = (t < NTERM) ? 1.0f / (sqrtf(s) + 1e-6f) : 0.0f;
}

// ---------------- Stage C: out[pair] = dot(vt[pair], invn[b]) --------------
__global__ __launch_bounds__(128) void cac_stageC(const float* __restrict__ vt,
                                                  const float* __restrict__ invn,
                                                  float* __restrict__ out) {
    __shared__ __align__(16) float sinv[NROW];
    const int pair = blockIdx.x * 128 + threadIdx.x;   // 128 | 1024 -> same b
    const int b = pair >> 10;
    for (int i = threadIdx.x; i < NROW; i += 128)
        sinv[i] = invn[b * NROW + i];                  // pads are 0
    __syncthreads();
    const float4* row = (const float4*)(vt + (size_t)pair * NROW);  // 640B-aligned
    const float4* w4 = (const float4*)sinv;
    float acc = 0.0f;
    #pragma unroll
    for (int i = 0; i < NROW / 4; ++i) {
        float4 v = row[i], w = w4[i];                  // w: LDS broadcast
        acc += v.x * w.x + v.y * w.y + v.z * w.z + v.w * w.w;
    }
    out[pair] = acc;
}

extern "C" void kernel_launch(void* const* d_in, const int* in_sizes, int n_in,
                              void* d_out, int out_size, void* d_ws, size_t ws_size,
                              hipStream_t stream) {
    const float* x = (const float*)d_in[0];
    float* out = (float*)d_out;

    float* vt      = (float*)d_ws;                                 // 32768*160 f32 = 21.0 MB
    float* partial = vt + (size_t)B_DIM * C_DIM * NROW;            //  8192*160 f32 =  5.2 MB
    float* invn    = partial + (size_t)8192 * NROW;                //    32*160 f32

    cac_stageA<<<(B_DIM * C_DIM) / 4, 256, 0, stream>>>(x, vt, partial);
    cac_stageB<<<B_DIM, 192, 0, stream>>>(partial, invn);
    cac_stageC<<<(B_DIM * C_DIM) / 128, 128, 0, stream>>>(vt, invn, out);
}

// Round 6
// 162.247 us; speedup vs baseline: 1.3970x; 1.0337x over previous
//
#include <hip/hip_runtime.h>
#include <math.h>

// Problem constants
#define B_DIM 32
#define C_DIM 1024
#define MAP 784
#define NMASK 153
#define NTERM 154          // 153 masks + global-max term
#define NROW 192           // padded row length (3 x 64 lanes; pads = 0)
#define NBIN 77            // 0=center, 1 + q*19 + (r-1)
#define DUMMY_BIN 77
#define MAX1 28            // slots for each lane's primary bin
#define MAX2 6             // slots for secondary (small) bins on lanes 51..63
#define MPW 8              // maps per wave; 1024 blocks x 4 waves x 8 = 32768

// ---------------------------------------------------------------------------
// Compile-time gather schedule, bank-aware (verified rounds 3-4, unchanged).
// ---------------------------------------------------------------------------
struct Sched {
    unsigned short off1[MAX1][64];  // [slot][lane] byte offset, primary bin
    unsigned short off2[MAX2][64];  // [slot][lane] byte offset, secondary bin
    unsigned char  binA[64];
    unsigned char  binB[64];        // DUMMY_BIN for lanes without a 2nd bin
    bool ok;
};

constexpr Sched build_sched() {
    Sched S{};
    S.ok = true;
    short px[NBIN][40] = {};
    int   n[NBIN] = {};
    for (int i = 0; i < 28; ++i)
        for (int j = 0; j < 28; ++j) {
            int dy = i - 14, dx = j - 14, r2 = dx * dx + dy * dy;
            int p = i * 28 + j;
            if (r2 == 0) { px[0][n[0]++] = (short)p; continue; }
            if (r2 > 361) continue;            // r2>361: in NO mask
            int r = 0; while (r * r < r2) ++r; // ceil(sqrt), 1..19
            const int sx[4] = {1, -1, 1, -1}, sy[4] = {1, 1, -1, -1};
            for (int q = 0; q < 4; ++q)
                if (sx[q] * dx >= 0 && sy[q] * dy >= 0) {
                    int b = 1 + q * 19 + (r - 1);
                    if (n[b] >= 40) { S.ok = false; continue; }
                    px[b][n[b]++] = (short)p;
                }
        }
    int ord[NBIN] = {};
    for (int k = 0; k < NBIN; ++k) ord[k] = k;
    for (int a = 0; a < NBIN; ++a) {
        int best = a;
        for (int c = a + 1; c < NBIN; ++c)
            if (n[ord[c]] > n[ord[best]]) best = c;
        int t = ord[a]; ord[a] = ord[best]; ord[best] = t;
    }
    for (int l = 0; l < 64; ++l) {
        S.binA[l] = (unsigned char)ord[l];
        S.binB[l] = (l >= 51) ? (unsigned char)ord[64 + (l - 51)]
                              : (unsigned char)DUMMY_BIN;
        if (n[ord[l]] > MAX1) S.ok = false;
        if (l >= 51 && n[ord[64 + (l - 51)]] > MAX2) S.ok = false;
    }
    {   // greedy bank-aware placement, primary loop
        bool used[64][40] = {};
        for (int s = 0; s < MAX1; ++s) {
            int bankcnt[32] = {};
            for (int l = 0; l < 64; ++l) {
                int bin = S.binA[l], cnt = n[bin];
                int bestp = 0, bestload = 1 << 30; bool haveUnused = false;
                for (int t = 0; t < cnt; ++t)
                    if (!used[l][t]) {
                        int load = bankcnt[px[bin][t] % 32];
                        if (!haveUnused || load < bestload) { haveUnused = true; bestload = load; bestp = t; }
                    }
                if (!haveUnused)
                    for (int t = 0; t < cnt; ++t) {
                        int load = bankcnt[px[bin][t] % 32];
                        if (load < bestload) { bestload = load; bestp = t; }
                    }
                int p = px[bin][bestp];
                if (haveUnused) used[l][bestp] = true;
                S.off1[s][l] = (unsigned short)(p * 4);
                bankcnt[p % 32]++;
            }
        }
        for (int l = 0; l < 64; ++l)
            for (int t = 0; t < n[S.binA[l]]; ++t)
                if (!used[l][t]) S.ok = false;
    }
    {   // secondary loop
        bool used[64][40] = {};
        for (int s = 0; s < MAX2; ++s) {
            int bankcnt[32] = {};
            for (int l = 0; l < 64; ++l) {
                if (S.binB[l] == DUMMY_BIN) {
                    S.off2[s][l] = (unsigned short)((l % 32) * 4);
                    continue;
                }
                int bin = S.binB[l], cnt = n[bin];
                int bestp = 0, bestload = 1 << 30; bool haveUnused = false;
                for (int t = 0; t < cnt; ++t)
                    if (!used[l][t]) {
                        int load = bankcnt[px[bin][t] % 32];
                        if (!haveUnused || load < bestload) { haveUnused = true; bestload = load; bestp = t; }
                    }
                if (!haveUnused)
                    for (int t = 0; t < cnt; ++t) {
                        int load = bankcnt[px[bin][t] % 32];
                        if (load < bestload) { bestload = load; bestp = t; }
                    }
                int p = px[bin][bestp];
                if (haveUnused) used[l][bestp] = true;
                S.off2[s][l] = (unsigned short)(p * 4);
                bankcnt[p % 32]++;
            }
        }
        for (int l = 0; l < 64; ++l)
            if (S.binB[l] != DUMMY_BIN)
                for (int t = 0; t < n[S.binB[l]]; ++t)
                    if (!used[l][t]) S.ok = false;
    }
    return S;
}

static_assert(build_sched().ok, "schedule overflow / unplaced pixel");
__constant__ Sched d_sched = build_sched();

// sbuf per-wave layout: [0..76] bins, [77] dummy, [78..153] circles(q*19+r-1)
__device__ __forceinline__ int term_addr(int k) {
    if (k == 0) return 0;                    // center mask
    if (k >= NMASK) return DUMMY_BIN;        // 153 overridden w/ gmax; >153 -> 0
    int t = k - 1, q = (t >> 1) & 3, rm1 = t >> 3;
    return (t & 1) ? 78 + q * 19 + rm1       // circle
                   : 1 + q * 19 + rm1;       // ring
}

// ---------------- K1: rows -> vt (coalesced) + per-block sq partials -------
__global__ __launch_bounds__(256) void cac_k1(const float* __restrict__ x,
                                              float* __restrict__ vt,
                                              float* __restrict__ partial) {
    __shared__ __align__(16) float smap[4][MAP];
    __shared__ float sbuf[4][160];           // bins + circles per wave
    __shared__ float ssqred[4][NROW];

    const int wave = threadIdx.x >> 6;
    const int lane = threadIdx.x & 63;
    const int pair0 = blockIdx.x * 32 + wave * MPW;

    // hoisted per-lane constants
    const int linA = lane % 19;                          // segment pos (q0-q2)
    const bool inA = lane < 57, inB = lane < 19;
    const int rbA = 1 + lane;                            // lanes>=57 read q3: harmless
    const int rbB = inB ? 58 + lane : DUMMY_BIN;
    const int a0 = term_addr(lane);
    const int a1 = term_addr(lane + 64);
    const int a2 = term_addr(lane + 128);

    // prefetch map 0
    const float4 NEG4 = make_float4(-INFINITY, -INFINITY, -INFINITY, -INFINITY);
    const float4* xp4 = (const float4*)(x + (size_t)pair0 * MAP);
    float4 t0 = xp4[lane], t1 = xp4[64 + lane], t2 = xp4[128 + lane];
    float4 t3 = NEG4;
    if (lane < 4) t3 = xp4[192 + lane];

    float* smw = smap[wave];
    float* sbw = sbuf[wave];
    float sq0 = 0.0f, sq1 = 0.0f, sq2 = 0.0f;

    #pragma unroll
    for (int m = 0; m < MPW; ++m) {
        ((float4*)smw)[lane]       = t0;
        ((float4*)smw)[64 + lane]  = t1;
        ((float4*)smw)[128 + lane] = t2;
        if (lane < 4) ((float4*)smw)[192 + lane] = t3;
        float gmax = fmaxf(fmaxf(fmaxf(t0.x, t0.y), fmaxf(t0.z, t0.w)),
                           fmaxf(fmaxf(t1.x, t1.y), fmaxf(t1.z, t1.w)));
        gmax = fmaxf(gmax, fmaxf(fmaxf(t2.x, t2.y), fmaxf(t2.z, t2.w)));
        gmax = fmaxf(gmax, fmaxf(fmaxf(t3.x, t3.y), fmaxf(t3.z, t3.w)));

        if (m < MPW - 1) {   // software-pipeline next map's global loads
            const float4* np4 = (const float4*)(x + (size_t)(pair0 + m + 1) * MAP);
            t0 = np4[lane]; t1 = np4[64 + lane]; t2 = np4[128 + lane];
            t3 = NEG4;
            if (lane < 4) t3 = np4[192 + lane];
        }
        __builtin_amdgcn_wave_barrier();     // keep LDS writes before reads

        // bank-scheduled gather (init 0 == masked-max clamp)
        const char* base = (const char*)smw;
        float m1 = 0.0f, m2v = 0.0f;
        #pragma unroll
        for (int s = 0; s < MAX1; ++s)
            m1 = fmaxf(m1, *(const float*)(base + d_sched.off1[s][lane]));
        #pragma unroll
        for (int s = 0; s < MAX2; ++s)
            m2v = fmaxf(m2v, *(const float*)(base + d_sched.off2[s][lane]));
        sbw[d_sched.binA[lane]] = m1;
        sbw[d_sched.binB[lane]] = m2v;       // dummy slot absorbs pad lanes

        #pragma unroll
        for (int off = 32; off; off >>= 1)
            gmax = fmaxf(gmax, __shfl_xor(gmax, off, 64));
        __builtin_amdgcn_wave_barrier();

        // segmented shuffle prefix-max over rings -> circles
        float cval = sbw[0];
        float rA = fmaxf(sbw[rbA], cval);    // rings: q=lane/19, r=lane%19+1
        float rB = fmaxf(sbw[rbB], cval);    // q3 rings on lanes 0..18
        #pragma unroll
        for (int s = 1; s <= 16; s <<= 1) {
            float uA = __shfl_up(rA, s, 64);
            float uB = __shfl_up(rB, s, 64);
            if (linA >= s) rA = fmaxf(rA, uA);
            if (lane >= s) rB = fmaxf(rB, uB);
        }
        if (inA) sbw[78 + lane] = rA;
        if (inB) sbw[135 + lane] = rB;
        __builtin_amdgcn_wave_barrier();

        // terms from one LDS read each
        float r0 = sbw[a0];
        float r1 = sbw[a1];
        float r2 = sbw[a2];
        r2 = (lane == 25) ? gmax : (lane < 26 ? r2 : 0.0f);  // k=153 / pads

        float* rowp = vt + (size_t)(pair0 + m) * NROW;
        rowp[lane]       = r0;
        rowp[64 + lane]  = r1;
        rowp[128 + lane] = r2;
        sq0 += r0 * r0; sq1 += r1 * r1; sq2 += r2 * r2;
        __builtin_amdgcn_wave_barrier();     // don't let next map's bin writes race
    }

    ssqred[wave][lane]       = sq0;
    ssqred[wave][lane + 64]  = sq1;
    ssqred[wave][lane + 128] = sq2;
    __syncthreads();
    if (threadIdx.x < NROW) {
        int t = threadIdx.x;
        partial[(size_t)blockIdx.x * NROW + t] =
            ssqred[0][t] + ssqred[1][t] + ssqred[2][t] + ssqred[3][t];
    }
}

// ---------------- K2: fused norm-reduce + dot ------------------------------
// 256 blocks x 256 threads; block handles 128 consecutive pairs (same b).
__global__ __launch_bounds__(256) void cac_k2(const float* __restrict__ vt,
                                              const float* __restrict__ partial,
                                              float* __restrict__ out) {
    __shared__ __align__(16) float sinv[NROW];
    const int b = blockIdx.x >> 3;           // 8 blocks per b

    if (threadIdx.x < NROW) {                // redundant per-b norm reduce (24KB, L2)
        int t = threadIdx.x;
        const float* p = partial + (size_t)(b * 32) * NROW + t;
        float s = 0.0f;
        #pragma unroll
        for (int j = 0; j < 32; ++j) s += p[j * NROW];
        sinv[t] = (t < NTERM) ? 1.0f / (sqrtf(s) + 1e-6f) : 0.0f;
    }
    __syncthreads();

    const int local = threadIdx.x >> 1;      // 0..127
    const int half  = threadIdx.x & 1;
    const int pair  = blockIdx.x * 128 + local;
    const float4* row = (const float4*)(vt + (size_t)pair * NROW + half * 96);
    const float4* w4  = (const float4*)sinv + half * 24;
    float acc = 0.0f;
    #pragma unroll
    for (int i = 0; i < 24; ++i) {
        float4 v = row[i], w = w4[i];
        acc += v.x * w.x + v.y * w.y + v.z * w.z + v.w * w.w;
    }
    acc += __shfl_xor(acc, 1, 64);
    if (!half) out[pair] = acc;
}

extern "C" void kernel_launch(void* const* d_in, const int* in_sizes, int n_in,
                              void* d_out, int out_size, void* d_ws, size_t ws_size,
                              hipStream_t stream) {
    const float* x = (const float*)d_in[0];
    float* out = (float*)d_out;

    float* vt      = (float*)d_ws;                           // 32768*192 f32 = 25.2 MB
    float* partial = vt + (size_t)B_DIM * C_DIM * NROW;      //  1024*192 f32 = 786 KB

    cac_k1<<<1024, 256, 0, stream>>>(x, vt, partial);
    cac_k2<<<256, 256, 0, stream>>>(vt, partial, out);
}